// Round 3
// baseline (158.173 us; speedup 1.0000x reference)
//
#include <hip/hip_runtime.h>
#include <float.h>

// Chamfer distance, two-pass.
// Pass 1: block = (batch, dir, target-slice). 256 threads x 16 queries each
//   (8 float2 packs, whole N=4096). Targets staged in LDS as (x,y,z,||t||^2),
//   broadcast-read b128, math forced to v_pk_fma_f32 (op_sel dword broadcast)
//   + v_min3_f32: 2 VALU insts per pair. Partial per-query mins -> ws.
// Pass 2: min across slices, mean, atomicAdd.
// B=32, N=M=4096, C=3, fp32.

#define BLK 256
#define NP  8                       // float2 query packs per thread

typedef float f2 __attribute__((ext_vector_type(2)));
typedef float f4 __attribute__((ext_vector_type(4)));

struct __align__(16) F4 { float x, y, z, s; };

// d = nqz * bcast(zs.lo=z) + bcast(zs.hi=s)
__device__ __forceinline__ f2 pk_dist_init(f2 nqz, f2 zs) {
    f2 d;
    asm("v_pk_fma_f32 %0, %1, %2, %2 op_sel:[0,0,1] op_sel_hi:[1,0,1]"
        : "=v"(d) : "v"(nqz), "v"(zs));
    return d;
}
// d += nqy * bcast(xy.hi=y)
__device__ __forceinline__ void pk_fma_bhi(f2& d, f2 nqy, f2 xy) {
    asm("v_pk_fma_f32 %0, %1, %2, %0 op_sel:[0,1,0] op_sel_hi:[1,1,1]"
        : "+v"(d) : "v"(nqy), "v"(xy));
}
// d += nqx * bcast(xy.lo=x)
__device__ __forceinline__ void pk_fma_blo(f2& d, f2 nqx, f2 xy) {
    asm("v_pk_fma_f32 %0, %1, %2, %0 op_sel:[0,0,0] op_sel_hi:[1,0,1]"
        : "+v"(d) : "v"(nqx), "v"(xy));
}
__device__ __forceinline__ void min3(float& m, float a, float b) {
    asm("v_min3_f32 %0, %0, %1, %2" : "+v"(m) : "v"(a), "v"(b));
}

template <int SLICES>
__global__ __launch_bounds__(BLK)
void chamfer_partial(const float* __restrict__ x,
                     const float* __restrict__ recon,
                     float* __restrict__ ws,
                     int B, int N, int M)
{
    constexpr int MSL = 4096 / SLICES;          // targets per slice
    const int dir = blockIdx.y;                 // 0: q=x,t=recon ; 1: q=recon,t=x
    const float* q = (dir == 0) ? x : recon;
    const float* t = (dir == 0) ? recon : x;

    const int slice = blockIdx.x % SLICES;
    const int b     = blockIdx.x / SLICES;
    const int tid   = threadIdx.x;

    __shared__ F4 lds[MSL];

    // Stage this slice's targets (coalesced flat copy), then fill ||t||^2.
    const float* src = t + ((size_t)b * M + (size_t)slice * MSL) * 3;
    for (int e = tid; e < MSL * 3; e += BLK) {
        int m = e / 3, c = e - 3 * m;
        ((float*)&lds[m])[c] = src[e];
    }
    __syncthreads();
    for (int m = tid; m < MSL; m += BLK) {
        F4 p = lds[m];
        lds[m].s = p.x * p.x + p.y * p.y + p.z * p.z;
    }
    __syncthreads();

    // 16 queries/thread as 8 float2 packs: precompute -2q and ||q||^2.
    f2 nqx[NP], nqy[NP], nqz[NP], q2[NP];
    float mn_lo[NP], mn_hi[NP];
    const float* qb = q + (size_t)b * N * 3;
    #pragma unroll
    for (int i = 0; i < NP; ++i) {
        int n0 = (2 * i) * BLK + tid;
        const float* qp0 = qb + (size_t)n0 * 3;
        const float* qp1 = qp0 + 3 * BLK;
        f2 ax = { qp0[0], qp1[0] };
        f2 ay = { qp0[1], qp1[1] };
        f2 az = { qp0[2], qp1[2] };
        nqx[i] = -2.0f * ax;
        nqy[i] = -2.0f * ay;
        nqz[i] = -2.0f * az;
        q2[i]  = ax * ax + ay * ay + az * az;
        mn_lo[i] = FLT_MAX;
        mn_hi[i] = FLT_MAX;
    }

    // Main loop: 2 targets per iter; 1 ds_read_b128 per target amortized over
    // 16 queries; per pack: 6 pk_fma + 2 min3 covering 4 pairs.
    #pragma unroll 4
    for (int m = 0; m < MSL; m += 2) {
        f4 p0 = *reinterpret_cast<const f4*>(&lds[m]);
        f4 p1 = *reinterpret_cast<const f4*>(&lds[m + 1]);
        f2 xy0 = __builtin_shufflevector(p0, p0, 0, 1);
        f2 zs0 = __builtin_shufflevector(p0, p0, 2, 3);
        f2 xy1 = __builtin_shufflevector(p1, p1, 0, 1);
        f2 zs1 = __builtin_shufflevector(p1, p1, 2, 3);
        #pragma unroll
        for (int i = 0; i < NP; ++i) {
            f2 da = pk_dist_init(nqz[i], zs0);
            pk_fma_bhi(da, nqy[i], xy0);
            pk_fma_blo(da, nqx[i], xy0);
            f2 db = pk_dist_init(nqz[i], zs1);
            pk_fma_bhi(db, nqy[i], xy1);
            pk_fma_blo(db, nqx[i], xy1);
            min3(mn_lo[i], da.x, db.x);
            min3(mn_hi[i], da.y, db.y);
        }
    }

    // Partial result per query: min + ||q||^2. Layout ws[slice][dir][b][n].
    size_t wbase = ((size_t)slice * 2 + dir) * (size_t)B * N + (size_t)b * N;
    #pragma unroll
    for (int i = 0; i < NP; ++i) {
        ws[wbase + (2 * i) * BLK + tid]     = mn_lo[i] + q2[i].x;
        ws[wbase + (2 * i + 1) * BLK + tid] = mn_hi[i] + q2[i].y;
    }
}

__global__ __launch_bounds__(BLK)
void chamfer_reduce(const float* __restrict__ ws,
                    float* __restrict__ out,
                    int slices, float scale)
{
    const size_t Q = 2u * 32u * 4096u;          // queries, both dirs
    size_t t = (size_t)blockIdx.x * BLK + threadIdx.x;

    float v = ws[t];
    for (int s = 1; s < slices; ++s)
        v = fminf(v, ws[(size_t)s * Q + t]);

    #pragma unroll
    for (int off = 32; off > 0; off >>= 1)
        v += __shfl_down(v, off, 64);

    __shared__ float red[BLK / 64];
    int tid = threadIdx.x;
    if ((tid & 63) == 0) red[tid >> 6] = v;
    __syncthreads();
    if (tid == 0) {
        float s = 0.0f;
        #pragma unroll
        for (int w = 0; w < BLK / 64; ++w) s += red[w];
        atomicAdd(out, s * scale);
    }
}

extern "C" void kernel_launch(void* const* d_in, const int* in_sizes, int n_in,
                              void* d_out, int out_size, void* d_ws, size_t ws_size,
                              hipStream_t stream) {
    const float* x     = (const float*)d_in[0];
    const float* recon = (const float*)d_in[1];
    float* out = (float*)d_out;
    float* ws  = (float*)d_ws;

    const int B = 32, N = 4096, M = 4096;
    const float scale = 1.0f / ((float)B * (float)N);
    const size_t Q = 2ull * B * N;               // 262144 partials per slice

    hipMemsetAsync(out, 0, sizeof(float), stream);

    // Pick slice count by available workspace (more slices = more blocks).
    int slices;
    if      (ws_size >= 16 * Q * sizeof(float)) slices = 16;
    else if (ws_size >=  8 * Q * sizeof(float)) slices = 8;
    else                                        slices = 4;

    dim3 grid1(B * slices, 2);
    if (slices == 16)
        chamfer_partial<16><<<grid1, BLK, 0, stream>>>(x, recon, ws, B, N, M);
    else if (slices == 8)
        chamfer_partial<8><<<grid1, BLK, 0, stream>>>(x, recon, ws, B, N, M);
    else
        chamfer_partial<4><<<grid1, BLK, 0, stream>>>(x, recon, ws, B, N, M);

    dim3 grid2(Q / BLK);
    chamfer_reduce<<<grid2, BLK, 0, stream>>>(ws, out, slices, scale);
}

// Round 4
// 103.598 us; speedup vs baseline: 1.5268x; 1.5268x over previous
//
#include <hip/hip_runtime.h>
#include <float.h>
#include <stdint.h>

// Chamfer distance via MFMA (bf16 hi/lo compensated split).
// d[n][m] = ||t_m||^2 - 2 q_n . t_m  + ||q_n||^2(added in epilogue)
// One mfma_f32_32x32x16_bf16 computes a 32q x 32t tile of (tt - 2q.t):
//   A k-slots (per query row, c = -2q):  [chx chy chz clx cly clz chx chy |
//                                         chz 1 1 clx cly clz 0 0]
//   B k-slots (per target col):          [bhx bhy bhz bhx bhy bhz blx bly |
//                                         blz tth ttl blx bly blz 0 0]
//   sum = ch.bh + cl.bh + ch.bl + tt(h+l) + cl.bl  ~= tt - 2q.t  (err ~1e-4)
// B fragments prepacked per target point by prep_kernel into ws (8 MB):
//   H0 region: records for lanes 0-31 (k=0..7), H1: lanes 32-63 (k=8..15).
// Main loop: global_load_dwordx4 -> mfma -> v_min. No barriers.

typedef short bf16x8 __attribute__((ext_vector_type(8)));
typedef float f32x16 __attribute__((ext_vector_type(16)));

#define BLK 256
#define ONE_BF 0x3F80u

__device__ __forceinline__ uint32_t bf16_rne(float f) {
    uint32_t u = __builtin_bit_cast(uint32_t, f);
    return (u + 0x7FFFu + ((u >> 16) & 1u)) >> 16;
}
__device__ __forceinline__ float bf16f(uint32_t h) {
    return __builtin_bit_cast(float, h << 16);
}

// ---- prep: 262144 points (arr0 = x, arr1 = recon), 16B H0 + 16B H1 each.
__global__ __launch_bounds__(BLK)
void prep_kernel(const float* __restrict__ x, const float* __restrict__ recon,
                 uint32_t* __restrict__ ws)
{
    int tid = blockIdx.x * BLK + threadIdx.x;     // 0..262143
    int arr = tid >> 17;
    int p   = tid & 131071;
    const float* s = arr ? recon : x;
    float a = s[3 * p], b = s[3 * p + 1], c = s[3 * p + 2];
    uint32_t hx = bf16_rne(a), hy = bf16_rne(b), hz = bf16_rne(c);
    uint32_t lx = bf16_rne(a - bf16f(hx));
    uint32_t ly = bf16_rne(b - bf16f(hy));
    uint32_t lz = bf16_rne(c - bf16f(hz));
    float tt = a * a + b * b + c * c;
    uint32_t th = bf16_rne(tt);
    uint32_t tl = bf16_rne(tt - bf16f(th));
    uint4 H0 = make_uint4(hx | (hy << 16), hz | (hx << 16),
                          hy | (hz << 16), lx | (ly << 16));
    uint4 H1 = make_uint4(lz | (th << 16), tl | (lx << 16),
                          ly | (lz << 16), 0u);
    ((uint4*)ws)[tid]          = H0;              // H0 region: rec 0..262143
    ((uint4*)ws)[262144 + tid] = H1;              // H1 region
}

// ---- main: grid (16 qblocks * 32 batches, 2 dirs), 256 thr = 4 waves.
// Wave owns 64 queries (2 x 32-row MFMA blocks), loops all 4096 targets.
__global__ __launch_bounds__(BLK, 4)
void chamfer_mfma(const float* __restrict__ x, const float* __restrict__ recon,
                  const uint32_t* __restrict__ ws, float* __restrict__ out,
                  float scale)
{
    const int dir = blockIdx.y;
    const int qb  = blockIdx.x & 15;
    const int b   = blockIdx.x >> 4;
    const float* qsrc = dir ? recon : x;          // queries
    const int arrT = dir ? 0 : 1;                 // targets: dir0->recon(arr1)

    const int tid  = threadIdx.x;
    const int wave = tid >> 6;
    const int lane = tid & 63;
    const int l31  = lane & 31;
    const int lh   = lane >> 5;

    // A fragments (one-time): row = l31 within each 32-row block.
    bf16x8 A0, A1;
    {
        int n0 = qb * 256 + wave * 64 + l31;
        #pragma unroll
        for (int rb = 0; rb < 2; ++rb) {
            const float* qp = qsrc + ((size_t)b * 4096 + n0 + rb * 32) * 3;
            float cx = -2.f * qp[0], cy = -2.f * qp[1], cz = -2.f * qp[2];
            uint32_t hx = bf16_rne(cx), hy = bf16_rne(cy), hz = bf16_rne(cz);
            uint32_t lx = bf16_rne(cx - bf16f(hx));
            uint32_t ly = bf16_rne(cy - bf16f(hy));
            uint32_t lz = bf16_rne(cz - bf16f(hz));
            uint32_t w0, w1, w2, w3;
            if (lh == 0) {
                w0 = hx | (hy << 16); w1 = hz | (lx << 16);
                w2 = ly | (lz << 16); w3 = hx | (hy << 16);
            } else {
                w0 = hz | (ONE_BF << 16); w1 = ONE_BF | (lx << 16);
                w2 = ly | (lz << 16);     w3 = 0u;
            }
            union { uint4 u; bf16x8 v; } cvt;
            cvt.u = make_uint4(w0, w1, w2, w3);
            if (rb == 0) A0 = cvt.v; else A1 = cvt.v;
        }
    }

    f32x16 zc = {0,0,0,0,0,0,0,0,0,0,0,0,0,0,0,0};
    float rmn0[16], rmn1[16];
    #pragma unroll
    for (int j = 0; j < 16; ++j) { rmn0[j] = FLT_MAX; rmn1[j] = FLT_MAX; }

    // B-fragment pointer: lane half picks H0/H1 region; col = l31.
    const uint4* rec = (const uint4*)ws
        + (size_t)lh * 262144 + (size_t)arrT * 131072 + (size_t)b * 4096 + l31;

    #pragma unroll 2
    for (int it = 0; it < 128; ++it) {            // 32 targets per iter
        union { uint4 u; bf16x8 v; } Bf;
        Bf.u = rec[it * 32];
        f32x16 d0 = __builtin_amdgcn_mfma_f32_32x32x16_bf16(A0, Bf.v, zc, 0, 0, 0);
        f32x16 d1 = __builtin_amdgcn_mfma_f32_32x32x16_bf16(A1, Bf.v, zc, 0, 0, 0);
        #pragma unroll
        for (int j = 0; j < 16; ++j) {
            rmn0[j] = fminf(rmn0[j], d0[j]);
            rmn1[j] = fminf(rmn1[j], d1[j]);
        }
    }

    // Epilogue: per-query min across 32 cols via LDS, +||q||^2, block sum.
    __shared__ float lmin[256][33];
    #pragma unroll
    for (int j = 0; j < 16; ++j) {
        int rl = (j & 3) + 8 * (j >> 2) + 4 * lh;  // verified 32x32 C/D row
        lmin[wave * 64 + rl][l31]      = rmn0[j];
        lmin[wave * 64 + 32 + rl][l31] = rmn1[j];
    }
    __syncthreads();

    float m = lmin[tid][0];
    #pragma unroll
    for (int c = 1; c < 32; ++c) m = fminf(m, lmin[tid][c]);

    const float* qp = qsrc + ((size_t)b * 4096 + qb * 256 + tid) * 3;
    float v = m + qp[0] * qp[0] + qp[1] * qp[1] + qp[2] * qp[2];

    #pragma unroll
    for (int off = 32; off > 0; off >>= 1)
        v += __shfl_down(v, off, 64);
    __shared__ float red[4];
    if (lane == 0) red[wave] = v;
    __syncthreads();
    if (tid == 0)
        atomicAdd(out, (red[0] + red[1] + red[2] + red[3]) * scale);
}

extern "C" void kernel_launch(void* const* d_in, const int* in_sizes, int n_in,
                              void* d_out, int out_size, void* d_ws, size_t ws_size,
                              hipStream_t stream) {
    const float* x     = (const float*)d_in[0];
    const float* recon = (const float*)d_in[1];
    float* out = (float*)d_out;

    const float scale = 1.0f / (32.0f * 4096.0f);

    hipMemsetAsync(out, 0, sizeof(float), stream);

    prep_kernel<<<1024, BLK, 0, stream>>>(x, recon, (uint32_t*)d_ws);

    dim3 g(512, 2);   // 16 qblocks * 32 batches, 2 directions
    chamfer_mfma<<<g, BLK, 0, stream>>>(x, recon, (const uint32_t*)d_ws,
                                        out, scale);
}